// Round 1
// baseline (1803.814 us; speedup 1.0000x reference)
//
#include <hip/hip_runtime.h>
#include <hip/hip_bf16.h>

#define D_MODEL 256
#define N_LAYER 16
#define VOCAB 24
#define D_INNER 512
#define D_STATE 16
#define D_CONV 4
#define DT_RANK 16
#define BATCH 2
#define SEQ 2048
#define NTOK (BATCH*SEQ)   /* 4096 */
#define EPS 1e-5f
#define NC 128             /* scan chunks per sequence */
#define CL (SEQ/NC)        /* 16 tokens per chunk */
#define NSC (BATCH*D_INNER*D_STATE)      /* 16384 scan chains */

typedef __hip_bfloat16 bf16;
typedef __attribute__((ext_vector_type(8))) short short8;
typedef __attribute__((ext_vector_type(4))) float f32x4;

__device__ __forceinline__ float silu(float v) { return v / (1.f + __expf(-v)); }
__device__ __forceinline__ float bf2f(bf16 v) { return __bfloat162float(v); }
__device__ __forceinline__ float bfs2f(short s) {         // raw bf16 bits -> f32
    return __uint_as_float(((unsigned)(unsigned short)s) << 16);
}
__device__ __forceinline__ short bfr(float x) {           // f32 -> bf16 RNE
    unsigned u = __float_as_uint(x);
    return (short)((u + 0x7fffu + ((u >> 16) & 1u)) >> 16);
}

// ------------- ALL-layer weight pre-convert: f32 -> bf16, one pass
__global__ void k_wcvt_all(const float* __restrict__ in_w, const float* __restrict__ out_w,
                           const float* __restrict__ x_w, short* __restrict__ in_wb,
                           short* __restrict__ out_wb, short* __restrict__ x_wb) {
    int idx = blockIdx.x * 256 + threadIdx.x;      // 6,684,672 total
    if (idx < 4194304) {
        in_wb[idx] = bfr(in_w[idx]);
    } else if (idx < 4194304 + 2097152) {
        int j = idx - 4194304;
        out_wb[j] = bfr(out_w[j]);
    } else {
        int j = idx - 4194304 - 2097152;           // < 393216
        x_wb[j] = bfr(x_w[j]);
    }
}

// ---------------------------------------------------------------- embedding
__global__ void k_embed(const int* __restrict__ ids, const float* __restrict__ emb,
                        float* __restrict__ residual) {
    int idx = blockIdx.x * 256 + threadIdx.x;      // NTOK*256
    int tok = idx >> 8, c = idx & 255;
    residual[idx] = emb[ids[tok] * D_MODEL + c];
}

// ------------------------------------------- rmsnorm -> bf16 hn (shuffle reduce)
__global__ void k_rmsnorm(const float* __restrict__ residual, const float* __restrict__ w,
                          bf16* __restrict__ hn) {
    __shared__ float wred[4];
    int tok = blockIdx.x, c = threadIdx.x;
    float v = residual[tok * 256 + c];
    float s = v * v;
    #pragma unroll
    for (int off = 32; off >= 1; off >>= 1) s += __shfl_xor(s, off);
    if ((c & 63) == 0) wred[c >> 6] = s;
    __syncthreads();
    float tot = wred[0] + wred[1] + wred[2] + wred[3];
    float scale = rsqrtf(tot * (1.f / 256.f) + EPS);
    hn[tok * 256 + c] = __float2bfloat16(v * scale * w[c]);
}

// ---------------- gemm1 MFMA: [NTOK,256]bf16 @ [1024,256]^T bf16 -> xh/zb bf16
__global__ __launch_bounds__(256) void k_gemm1_mfma(const bf16* __restrict__ Abf,
                                                    const short* __restrict__ W16,
                                                    bf16* __restrict__ xh,
                                                    bf16* __restrict__ zb) {
    __shared__ short AsL[64 * 40];   // [row][40] bf16, pad 32->40
    __shared__ short WsL[64 * 40];
    const short* A16 = (const short*)Abf;
    const int bm = blockIdx.x * 64, bn = blockIdx.y * 64;
    const int tid = threadIdx.x;
    const int wave = tid >> 6, lane = tid & 63;
    const int wm = (wave & 1) * 32, wn = (wave >> 1) * 32;
    const int quad = lane >> 4, lr = lane & 15;
    const int srow = tid >> 2, skq = (tid & 3) * 8;
    f32x4 acc[2][2] = {};
    for (int k0 = 0; k0 < 256; k0 += 32) {
        short8 a8 = *(const short8*)(A16 + (size_t)(bm + srow) * 256 + k0 + skq);
        short8 w8 = *(const short8*)(W16 + (size_t)(bn + srow) * 256 + k0 + skq);
        __syncthreads();
        *(short8*)&AsL[srow * 40 + skq] = a8;
        *(short8*)&WsL[srow * 40 + skq] = w8;
        __syncthreads();
        short8 af[2], bf[2];
        #pragma unroll
        for (int i = 0; i < 2; i++) {
            af[i] = *(const short8*)&AsL[(wm + i * 16 + lr) * 40 + quad * 8];
            bf[i] = *(const short8*)&WsL[(wn + i * 16 + lr) * 40 + quad * 8];
        }
        #pragma unroll
        for (int mi = 0; mi < 2; mi++)
            #pragma unroll
            for (int ni = 0; ni < 2; ni++)
                acc[mi][ni] = __builtin_amdgcn_mfma_f32_16x16x32_bf16(
                    af[mi], bf[ni], acc[mi][ni], 0, 0, 0);
    }
    #pragma unroll
    for (int mi = 0; mi < 2; mi++) {
        #pragma unroll
        for (int ni = 0; ni < 2; ni++) {
            int gcol = bn + wn + ni * 16 + lr;
            #pragma unroll
            for (int r = 0; r < 4; r++) {
                int grow = bm + wm + mi * 16 + quad * 4 + r;
                float v = acc[mi][ni][r];
                if (bn < 512) xh[(size_t)grow * 512 + gcol] = __float2bfloat16(v);
                else          zb[(size_t)grow * 512 + gcol - 512] = __float2bfloat16(v);
            }
        }
    }
}

// ---------------- gemm2 MFMA: residual += [NTOK,512]bf16 @ [256,512]^T bf16
__global__ __launch_bounds__(256) void k_gemm2_mfma(const bf16* __restrict__ Abf,
                                                    const short* __restrict__ W16,
                                                    float* __restrict__ residual) {
    __shared__ short AsL[64 * 40];
    __shared__ short WsL[64 * 40];
    const short* A16 = (const short*)Abf;
    const int bm = blockIdx.x * 64, bn = blockIdx.y * 64;
    const int tid = threadIdx.x;
    const int wave = tid >> 6, lane = tid & 63;
    const int wm = (wave & 1) * 32, wn = (wave >> 1) * 32;
    const int quad = lane >> 4, lr = lane & 15;
    const int srow = tid >> 2, skq = (tid & 3) * 8;
    f32x4 acc[2][2] = {};
    for (int k0 = 0; k0 < 512; k0 += 32) {
        short8 a8 = *(const short8*)(A16 + (size_t)(bm + srow) * 512 + k0 + skq);
        short8 w8 = *(const short8*)(W16 + (size_t)(bn + srow) * 512 + k0 + skq);
        __syncthreads();
        *(short8*)&AsL[srow * 40 + skq] = a8;
        *(short8*)&WsL[srow * 40 + skq] = w8;
        __syncthreads();
        short8 af[2], bf[2];
        #pragma unroll
        for (int i = 0; i < 2; i++) {
            af[i] = *(const short8*)&AsL[(wm + i * 16 + lr) * 40 + quad * 8];
            bf[i] = *(const short8*)&WsL[(wn + i * 16 + lr) * 40 + quad * 8];
        }
        #pragma unroll
        for (int mi = 0; mi < 2; mi++)
            #pragma unroll
            for (int ni = 0; ni < 2; ni++)
                acc[mi][ni] = __builtin_amdgcn_mfma_f32_16x16x32_bf16(
                    af[mi], bf[ni], acc[mi][ni], 0, 0, 0);
    }
    #pragma unroll
    for (int mi = 0; mi < 2; mi++) {
        #pragma unroll
        for (int ni = 0; ni < 2; ni++) {
            int gcol = bn + wn + ni * 16 + lr;
            #pragma unroll
            for (int r = 0; r < 4; r++) {
                int grow = bm + wm + mi * 16 + quad * 4 + r;
                size_t idx = (size_t)grow * 256 + gcol;
                residual[idx] += acc[mi][ni][r];
            }
        }
    }
}

// ---------------- FUSED depthwise conv+silu  +  x_proj MFMA
// M-tile 32 tokens (128 blocks), N=64 (48 used), K=512.
// Conv output computed in-register during A staging; side-written to xb.
__global__ __launch_bounds__(256) void k_convxproj(const bf16* __restrict__ xh,
                                                   const float* __restrict__ cw,
                                                   const float* __restrict__ cb,
                                                   const short* __restrict__ W16,
                                                   bf16* __restrict__ xb,
                                                   float* __restrict__ dbc) {
    __shared__ short AsL[32 * 40];
    __shared__ short WsL[64 * 40];
    const int bm = blockIdx.x * 32;
    const int tid = threadIdx.x;
    const int wave = tid >> 6, lane = tid & 63;
    const int wm = (wave & 1) * 16, wn = (wave >> 1) * 32;
    const int quad = lane >> 4, lr = lane & 15;
    const int srow = tid >> 2, skq = (tid & 3) * 8;   // srow 0..63
    const int tok = bm + srow;                        // valid as A-row when srow<32
    const int l = tok & 2047;                         // pos within sequence
    f32x4 acc[2] = {};
    for (int k0 = 0; k0 < 512; k0 += 32) {
        short8 w8;
        if (srow < 48) w8 = *(const short8*)(W16 + (size_t)srow * 512 + k0 + skq);
        short8 cvt;
        if (srow < 32) {
            const int dbase = k0 + skq;
            float xv[4][8];
            #pragma unroll
            for (int i = 0; i < 4; i++) {
                int lt = l - 3 + i;
                if (lt >= 0) {
                    short8 r8 = *(const short8*)((const short*)xh +
                                   (size_t)(tok - 3 + i) * 512 + dbase);
                    #pragma unroll
                    for (int j = 0; j < 8; j++) xv[i][j] = bfs2f(r8[j]);
                } else {
                    #pragma unroll
                    for (int j = 0; j < 8; j++) xv[i][j] = 0.f;
                }
            }
            #pragma unroll
            for (int j = 0; j < 8; j++) {
                int d = dbase + j;
                float4 cwv = *(const float4*)(cw + d * 4);
                float a = cb[d] + xv[0][j] * cwv.x + xv[1][j] * cwv.y
                                + xv[2][j] * cwv.z + xv[3][j] * cwv.w;
                cvt[j] = bfr(silu(a));
            }
        }
        __syncthreads();
        if (srow < 32) {
            *(short8*)&AsL[srow * 40 + skq] = cvt;
            *(short8*)((short*)xb + (size_t)tok * 512 + k0 + skq) = cvt;
        }
        if (srow < 48) *(short8*)&WsL[srow * 40 + skq] = w8;
        __syncthreads();
        short8 af = *(const short8*)&AsL[(wm + lr) * 40 + quad * 8];
        #pragma unroll
        for (int ni = 0; ni < 2; ni++) {
            short8 bfv = *(const short8*)&WsL[(wn + ni * 16 + lr) * 40 + quad * 8];
            acc[ni] = __builtin_amdgcn_mfma_f32_16x16x32_bf16(af, bfv, acc[ni], 0, 0, 0);
        }
    }
    #pragma unroll
    for (int ni = 0; ni < 2; ni++) {
        int gcol = wn + ni * 16 + lr;
        if (gcol < 48) {
            #pragma unroll
            for (int r = 0; r < 4; r++) {
                int grow = bm + wm + quad * 4 + r;
                dbc[(size_t)grow * 48 + gcol] = acc[ni][r];
            }
        }
    }
}

// -------- scan phase A: thread = (b,d,chunk); dt recomputed identically in scanC,
// so no dt export. 16 s-states in registers.
__global__ __launch_bounds__(64) void k_scanA(const bf16* __restrict__ xb,
                                              const float* __restrict__ dbc,
                                              const float* __restrict__ dtw,
                                              const float* __restrict__ dtb,
                                              const float* __restrict__ a_log,
                                              float* __restrict__ Aprod,
                                              float* __restrict__ Hfin) {
    int gid = blockIdx.x * 64 + threadIdx.x;       // 1024*NC = 131072
    int bd = gid & 1023;                           // d fast -> coalesced
    int c = gid >> 10;
    int d = bd & 511, b = bd >> 9;
    float A[16], h[16], ap[16], wdt[16];
    #pragma unroll
    for (int q = 0; q < 4; q++)
        *(float4*)&wdt[q*4] = *(const float4*)(dtw + d * 16 + q * 4);
    #pragma unroll
    for (int s = 0; s < 16; s++) {
        A[s] = -__expf(a_log[d * 16 + s]);
        h[s] = 0.f; ap[s] = 1.f;
    }
    float bdt = dtb[d];
    int tok0 = b * SEQ + c * CL;
    const bf16* xp = xb + (size_t)tok0 * 512 + d;
    const float* rp = dbc + (size_t)tok0 * 48;
    for (int t = 0; t < CL; t++) {
        float rv[32];
        #pragma unroll
        for (int q = 0; q < 8; q++) *(float4*)&rv[q*4] = *(const float4*)(rp + t * 48 + q * 4);
        float dtr = bdt;
        #pragma unroll
        for (int r = 0; r < 16; r++) dtr = fmaf(rv[r], wdt[r], dtr);
        float dtv = (dtr > 20.f) ? dtr : __logf(1.f + __expf(dtr));
        float u = dtv * bf2f(xp[t * 512]);
        #pragma unroll
        for (int s = 0; s < 16; s++) {
            float dA = __expf(dtv * A[s]);
            h[s] = fmaf(dA, h[s], u * rv[16 + s]);
            ap[s] *= dA;
        }
    }
    float* Ap = Aprod + (size_t)c * NSC + bd * 16;
    float* Hp = Hfin  + (size_t)c * NSC + bd * 16;
    #pragma unroll
    for (int q = 0; q < 4; q++) {
        *(float4*)(Ap + q * 4) = make_float4(ap[q*4], ap[q*4+1], ap[q*4+2], ap[q*4+3]);
        *(float4*)(Hp + q * 4) = make_float4(h[q*4], h[q*4+1], h[q*4+2], h[q*4+3]);
    }
}

// ---------------- scan phase B: serial combine over chunks, register-batched
// prefetch (16 chunks in flight) + 256 blocks x 64 thr (1 wave on every CU)
__global__ __launch_bounds__(64) void k_scanB(const float* __restrict__ Aprod,
                                              float* __restrict__ Hfin) {
    int chain = blockIdx.x * 64 + threadIdx.x;     // NSC
    float h = 0.f;
    for (int cg = 0; cg < NC; cg += 16) {
        float a[16], f[16];
        #pragma unroll
        for (int j = 0; j < 16; j++) {
            size_t i = (size_t)(cg + j) * NSC + chain;
            a[j] = Aprod[i];
            f[j] = Hfin[i];
        }
        #pragma unroll
        for (int j = 0; j < 16; j++) {
            size_t i = (size_t)(cg + j) * NSC + chain;
            Hfin[i] = h;
            h = fmaf(a[j], h, f[j]);
        }
    }
}

// -------- scan phase C: rescan from start state; dt recomputed bit-identically
// from dbc (same fmaf chain as scanA) -> no dtbuf round-trip.
__global__ __launch_bounds__(64) void k_scanC(const bf16* __restrict__ xb,
                                              const bf16* __restrict__ zb,
                                              const float* __restrict__ dbc,
                                              const float* __restrict__ dtw,
                                              const float* __restrict__ dtb,
                                              const float* __restrict__ a_log,
                                              const float* __restrict__ Dp,
                                              const float* __restrict__ Hstart,
                                              bf16* __restrict__ yb) {
    int gid = blockIdx.x * 64 + threadIdx.x;       // 131072
    int bd = gid & 1023;
    int c = gid >> 10;
    int d = bd & 511, b = bd >> 9;
    float A[16], h[16], wdt[16];
    const float* Hp = Hstart + (size_t)c * NSC + bd * 16;
    #pragma unroll
    for (int q = 0; q < 4; q++)
        *(float4*)&wdt[q*4] = *(const float4*)(dtw + d * 16 + q * 4);
    #pragma unroll
    for (int s = 0; s < 16; s++) {
        A[s] = -__expf(a_log[d * 16 + s]);
        h[s] = Hp[s];
    }
    float bdt = dtb[d];
    float Dv = Dp[d];
    int tok0 = b * SEQ + c * CL;
    const bf16* xp = xb + (size_t)tok0 * 512 + d;
    const bf16* zp = zb + (size_t)tok0 * 512 + d;
    const float* rp = dbc + (size_t)tok0 * 48;     // dt at +0, B at +16, C at +32
    bf16* yp = yb + (size_t)tok0 * 512 + d;
    for (int t = 0; t < CL; t++) {
        float rv[48];
        #pragma unroll
        for (int q = 0; q < 12; q++) *(float4*)&rv[q*4] = *(const float4*)(rp + t * 48 + q * 4);
        float dtr = bdt;
        #pragma unroll
        for (int r = 0; r < 16; r++) dtr = fmaf(rv[r], wdt[r], dtr);
        float dtv = (dtr > 20.f) ? dtr : __logf(1.f + __expf(dtr));
        float xv = bf2f(xp[t * 512]);
        float u = dtv * xv;
        float sum = 0.f;
        #pragma unroll
        for (int s = 0; s < 16; s++) {
            float dA = __expf(dtv * A[s]);
            h[s] = fmaf(dA, h[s], u * rv[16 + s]);
            sum = fmaf(h[s], rv[32 + s], sum);
        }
        float zv = bf2f(zp[t * 512]);
        yp[t * 512] = __float2bfloat16((sum + Dv * xv) * silu(zv));
    }
}

// ---------------------------------------------------------------- lm head
__global__ void k_head(const bf16* __restrict__ hn, const float* __restrict__ lw,
                       float* __restrict__ out) {
    int idx = blockIdx.x * 256 + threadIdx.x;      // NTOK*20 = 81920
    int tok = idx / 20, v = idx % 20;
    const short* a = (const short*)(hn + (size_t)tok * 256);
    const float* w = lw + (size_t)v * 256;
    float acc = 0.f;
    for (int k = 0; k < 256; k += 8) {
        short8 a8 = *(const short8*)(a + k);
        #pragma unroll
        for (int j = 0; j < 8; j++) acc = fmaf(bfs2f(a8[j]), w[k + j], acc);
    }
    out[idx] = acc;
}

extern "C" void kernel_launch(void* const* d_in, const int* in_sizes, int n_in,
                              void* d_out, int out_size, void* d_ws, size_t ws_size,
                              hipStream_t stream) {
    const int*   ids    = (const int*)d_in[0];
    const float* emb    = (const float*)d_in[1];
    const float* in_w   = (const float*)d_in[2];
    const float* conv_w = (const float*)d_in[3];
    const float* conv_b = (const float*)d_in[4];
    const float* x_w    = (const float*)d_in[5];
    const float* dt_w   = (const float*)d_in[6];
    const float* dt_b   = (const float*)d_in[7];
    const float* a_log  = (const float*)d_in[8];
    const float* d_skip = (const float*)d_in[9];
    const float* out_w  = (const float*)d_in[10];
    const float* norm_w = (const float*)d_in[11];
    const float* norm_f = (const float*)d_in[12];
    const float* lm_w   = (const float*)d_in[13];
    float* out = (float*)d_out;

    // ---- workspace layout (dtbuf slot retired, offsets kept stable) ----
    char* ws = (char*)d_ws;
    float* residual = (float*)(ws + 0);            // 4 MB
    bf16*  hn       = (bf16*) (ws + 4194304);      // 2 MB
    bf16*  xh       = (bf16*) (ws + 6291456);      // 4 MB (alias: yb)
    bf16*  zb       = (bf16*) (ws + 10485760);     // 4 MB
    bf16*  xb       = (bf16*) (ws + 14680064);     // 4 MB
    float* dbc      = (float*)(ws + 18874368);     // 768 KB
    float* Aprod    = (float*)(ws + 23855104);     // 8 MB
    float* Hfin     = (float*)(ws + 32243712);     // 8 MB
    short* in_wb    = (short*)(ws + 40632320);     // 8 MB  (16 layers bf16)
    short* out_wb   = (short*)(ws + 49020928);     // 4 MB
    short* x_wb     = (short*)(ws + 53215232);     // 768 KB -> end 54,001,664
    bf16*  yb       = xh;

    k_wcvt_all<<<6684672 / 256, 256, 0, stream>>>(in_w, out_w, x_w, in_wb, out_wb, x_wb);
    k_embed<<<(NTOK * 256) / 256, 256, 0, stream>>>(ids, emb, residual);

    for (int i = 0; i < N_LAYER; i++) {
        k_rmsnorm<<<NTOK, 256, 0, stream>>>(residual, norm_w + i * D_MODEL, hn);
        dim3 g1(NTOK / 64, 1024 / 64);
        k_gemm1_mfma<<<g1, 256, 0, stream>>>(hn, in_wb + (size_t)i * 262144, xh, zb);
        k_convxproj<<<NTOK / 32, 256, 0, stream>>>(
            xh, conv_w + (size_t)i * 512 * 4, conv_b + (size_t)i * 512,
            x_wb + (size_t)i * 24576, xb, dbc);
        k_scanA<<<(1024 * NC) / 64, 64, 0, stream>>>(
            xb, dbc, dt_w + (size_t)i * 512 * 16, dt_b + (size_t)i * 512,
            a_log + (size_t)i * 512 * 16, Aprod, Hfin);
        k_scanB<<<NSC / 64, 64, 0, stream>>>(Aprod, Hfin);
        k_scanC<<<(1024 * NC) / 64, 64, 0, stream>>>(
            xb, zb, dbc, dt_w + (size_t)i * 512 * 16, dt_b + (size_t)i * 512,
            a_log + (size_t)i * 512 * 16, d_skip + (size_t)i * 512, Hfin, yb);
        dim3 g2(NTOK / 64, 256 / 64);
        k_gemm2_mfma<<<g2, 256, 0, stream>>>(yb, out_wb + (size_t)i * 131072, residual);
    }

    k_rmsnorm<<<NTOK, 256, 0, stream>>>(residual, norm_f, hn);
    k_head<<<320, 256, 0, stream>>>(hn, lm_w, out);
}

// Round 2
// 1457.707 us; speedup vs baseline: 1.2374x; 1.2374x over previous
//
#include <hip/hip_runtime.h>
#include <hip/hip_bf16.h>

#define D_MODEL 256
#define N_LAYER 16
#define VOCAB 24
#define D_INNER 512
#define D_STATE 16
#define D_CONV 4
#define DT_RANK 16
#define BATCH 2
#define SEQ 2048
#define NTOK (BATCH*SEQ)   /* 4096 */
#define EPS 1e-5f
#define NC 128             /* scan chunks per sequence */
#define CL (SEQ/NC)        /* 16 tokens per chunk */
#define NSC (BATCH*D_INNER*D_STATE)      /* 16384 scan chains */

typedef __hip_bfloat16 bf16;
typedef __attribute__((ext_vector_type(8))) short short8;
typedef __attribute__((ext_vector_type(4))) float f32x4;

__device__ __forceinline__ float silu(float v) { return v / (1.f + __expf(-v)); }
__device__ __forceinline__ float bf2f(bf16 v) { return __bfloat162float(v); }
__device__ __forceinline__ float bfs2f(short s) {         // raw bf16 bits -> f32
    return __uint_as_float(((unsigned)(unsigned short)s) << 16);
}
__device__ __forceinline__ short bfr(float x) {           // f32 -> bf16 RNE
    unsigned u = __float_as_uint(x);
    return (short)((u + 0x7fffu + ((u >> 16) & 1u)) >> 16);
}

// ------------- ALL-layer weight pre-convert: f32 -> bf16, one pass
__global__ void k_wcvt_all(const float* __restrict__ in_w, const float* __restrict__ out_w,
                           const float* __restrict__ x_w, short* __restrict__ in_wb,
                           short* __restrict__ out_wb, short* __restrict__ x_wb) {
    int idx = blockIdx.x * 256 + threadIdx.x;      // 6,684,672 total
    if (idx < 4194304) {
        in_wb[idx] = bfr(in_w[idx]);
    } else if (idx < 4194304 + 2097152) {
        int j = idx - 4194304;
        out_wb[j] = bfr(out_w[j]);
    } else {
        int j = idx - 4194304 - 2097152;           // < 393216
        x_wb[j] = bfr(x_w[j]);
    }
}

// ---------------------------------------------------------------- embedding
__global__ void k_embed(const int* __restrict__ ids, const float* __restrict__ emb,
                        float* __restrict__ residual) {
    int idx = blockIdx.x * 256 + threadIdx.x;      // NTOK*256
    int tok = idx >> 8, c = idx & 255;
    residual[idx] = emb[ids[tok] * D_MODEL + c];
}

// ------------------------------------------- rmsnorm -> bf16 hn (shuffle reduce)
__global__ void k_rmsnorm(const float* __restrict__ residual, const float* __restrict__ w,
                          bf16* __restrict__ hn) {
    __shared__ float wred[4];
    int tok = blockIdx.x, c = threadIdx.x;
    float v = residual[tok * 256 + c];
    float s = v * v;
    #pragma unroll
    for (int off = 32; off >= 1; off >>= 1) s += __shfl_xor(s, off);
    if ((c & 63) == 0) wred[c >> 6] = s;
    __syncthreads();
    float tot = wred[0] + wred[1] + wred[2] + wred[3];
    float scale = rsqrtf(tot * (1.f / 256.f) + EPS);
    hn[tok * 256 + c] = __float2bfloat16(v * scale * w[c]);
}

// ---------------- gemm1 MFMA: [NTOK,256]bf16 @ [1024,256]^T bf16 -> xh/zb bf16
__global__ __launch_bounds__(256) void k_gemm1_mfma(const bf16* __restrict__ Abf,
                                                    const short* __restrict__ W16,
                                                    bf16* __restrict__ xh,
                                                    bf16* __restrict__ zb) {
    __shared__ short AsL[64 * 40];   // [row][40] bf16, pad 32->40
    __shared__ short WsL[64 * 40];
    const short* A16 = (const short*)Abf;
    const int bm = blockIdx.x * 64, bn = blockIdx.y * 64;
    const int tid = threadIdx.x;
    const int wave = tid >> 6, lane = tid & 63;
    const int wm = (wave & 1) * 32, wn = (wave >> 1) * 32;
    const int quad = lane >> 4, lr = lane & 15;
    const int srow = tid >> 2, skq = (tid & 3) * 8;
    f32x4 acc[2][2] = {};
    for (int k0 = 0; k0 < 256; k0 += 32) {
        short8 a8 = *(const short8*)(A16 + (size_t)(bm + srow) * 256 + k0 + skq);
        short8 w8 = *(const short8*)(W16 + (size_t)(bn + srow) * 256 + k0 + skq);
        __syncthreads();
        *(short8*)&AsL[srow * 40 + skq] = a8;
        *(short8*)&WsL[srow * 40 + skq] = w8;
        __syncthreads();
        short8 af[2], bf[2];
        #pragma unroll
        for (int i = 0; i < 2; i++) {
            af[i] = *(const short8*)&AsL[(wm + i * 16 + lr) * 40 + quad * 8];
            bf[i] = *(const short8*)&WsL[(wn + i * 16 + lr) * 40 + quad * 8];
        }
        #pragma unroll
        for (int mi = 0; mi < 2; mi++)
            #pragma unroll
            for (int ni = 0; ni < 2; ni++)
                acc[mi][ni] = __builtin_amdgcn_mfma_f32_16x16x32_bf16(
                    af[mi], bf[ni], acc[mi][ni], 0, 0, 0);
    }
    #pragma unroll
    for (int mi = 0; mi < 2; mi++) {
        #pragma unroll
        for (int ni = 0; ni < 2; ni++) {
            int gcol = bn + wn + ni * 16 + lr;
            #pragma unroll
            for (int r = 0; r < 4; r++) {
                int grow = bm + wm + mi * 16 + quad * 4 + r;
                float v = acc[mi][ni][r];
                if (bn < 512) xh[(size_t)grow * 512 + gcol] = __float2bfloat16(v);
                else          zb[(size_t)grow * 512 + gcol - 512] = __float2bfloat16(v);
            }
        }
    }
}

// ---------------- gemm2 MFMA: residual += [NTOK,512]bf16 @ [256,512]^T bf16
__global__ __launch_bounds__(256) void k_gemm2_mfma(const bf16* __restrict__ Abf,
                                                    const short* __restrict__ W16,
                                                    float* __restrict__ residual) {
    __shared__ short AsL[64 * 40];
    __shared__ short WsL[64 * 40];
    const short* A16 = (const short*)Abf;
    const int bm = blockIdx.x * 64, bn = blockIdx.y * 64;
    const int tid = threadIdx.x;
    const int wave = tid >> 6, lane = tid & 63;
    const int wm = (wave & 1) * 32, wn = (wave >> 1) * 32;
    const int quad = lane >> 4, lr = lane & 15;
    const int srow = tid >> 2, skq = (tid & 3) * 8;
    f32x4 acc[2][2] = {};
    for (int k0 = 0; k0 < 512; k0 += 32) {
        short8 a8 = *(const short8*)(A16 + (size_t)(bm + srow) * 512 + k0 + skq);
        short8 w8 = *(const short8*)(W16 + (size_t)(bn + srow) * 512 + k0 + skq);
        __syncthreads();
        *(short8*)&AsL[srow * 40 + skq] = a8;
        *(short8*)&WsL[srow * 40 + skq] = w8;
        __syncthreads();
        short8 af[2], bf[2];
        #pragma unroll
        for (int i = 0; i < 2; i++) {
            af[i] = *(const short8*)&AsL[(wm + i * 16 + lr) * 40 + quad * 8];
            bf[i] = *(const short8*)&WsL[(wn + i * 16 + lr) * 40 + quad * 8];
        }
        #pragma unroll
        for (int mi = 0; mi < 2; mi++)
            #pragma unroll
            for (int ni = 0; ni < 2; ni++)
                acc[mi][ni] = __builtin_amdgcn_mfma_f32_16x16x32_bf16(
                    af[mi], bf[ni], acc[mi][ni], 0, 0, 0);
    }
    #pragma unroll
    for (int mi = 0; mi < 2; mi++) {
        #pragma unroll
        for (int ni = 0; ni < 2; ni++) {
            int gcol = bn + wn + ni * 16 + lr;
            #pragma unroll
            for (int r = 0; r < 4; r++) {
                int grow = bm + wm + mi * 16 + quad * 4 + r;
                size_t idx = (size_t)grow * 256 + gcol;
                residual[idx] += acc[mi][ni][r];
            }
        }
    }
}

// ---------------- depthwise conv + silu: thread = (d, 4 consecutive tokens)
__global__ void k_conv(const bf16* __restrict__ xh, const float* __restrict__ cw,
                       const float* __restrict__ cb, bf16* __restrict__ xb) {
    int gid = blockIdx.x * 256 + threadIdx.x;      // 512 * NTOK/4 = 524288
    int d = gid & 511;
    int tq = gid >> 9;                             // 0..1023
    int tok0 = tq * 4;                             // 4 | 2048: no batch crossing
    int b = tok0 >> 11, l0 = tok0 & 2047;
    float4 cwv = *(const float4*)(cw + d * 4);
    float cbv = cb[d];
    const bf16* base = xh + ((size_t)(b << 11)) * 512 + d;
    float xv[7];
    #pragma unroll
    for (int i = 0; i < 7; i++) {
        int lt = l0 - 3 + i;
        xv[i] = (lt >= 0) ? bf2f(base[(size_t)lt * 512]) : 0.f;
    }
    bf16* dst = xb + (size_t)tok0 * 512 + d;
    #pragma unroll
    for (int t = 0; t < 4; t++) {
        float acc = cbv + xv[t] * cwv.x + xv[t+1] * cwv.y + xv[t+2] * cwv.z + xv[t+3] * cwv.w;
        dst[(size_t)t * 512] = __float2bfloat16(silu(acc));
    }
}

// ---------------- x_proj MFMA: dbc[NTOK,48] = xc[NTOK,512]bf16 @ xw[48,512]^T bf16
__global__ __launch_bounds__(256) void k_xproj_mfma(const bf16* __restrict__ Abf,
                                                    const short* __restrict__ W16,
                                                    float* __restrict__ dbc) {
    __shared__ short AsL[64 * 40];
    __shared__ short WsL[64 * 40];
    const short* A16 = (const short*)Abf;
    const int bm = blockIdx.x * 64;
    const int tid = threadIdx.x;
    const int wave = tid >> 6, lane = tid & 63;
    const int wm = (wave & 1) * 32, wn = (wave >> 1) * 32;
    const int quad = lane >> 4, lr = lane & 15;
    const int srow = tid >> 2, skq = (tid & 3) * 8;
    f32x4 acc[2][2] = {};
    for (int k0 = 0; k0 < 512; k0 += 32) {
        short8 a8 = *(const short8*)(A16 + (size_t)(bm + srow) * 512 + k0 + skq);
        short8 w8;
        if (srow < 48) w8 = *(const short8*)(W16 + (size_t)srow * 512 + k0 + skq);
        __syncthreads();
        *(short8*)&AsL[srow * 40 + skq] = a8;
        if (srow < 48) *(short8*)&WsL[srow * 40 + skq] = w8;
        __syncthreads();
        short8 af[2], bf[2];
        #pragma unroll
        for (int i = 0; i < 2; i++) {
            af[i] = *(const short8*)&AsL[(wm + i * 16 + lr) * 40 + quad * 8];
            bf[i] = *(const short8*)&WsL[(wn + i * 16 + lr) * 40 + quad * 8];
        }
        #pragma unroll
        for (int mi = 0; mi < 2; mi++)
            #pragma unroll
            for (int ni = 0; ni < 2; ni++)
                acc[mi][ni] = __builtin_amdgcn_mfma_f32_16x16x32_bf16(
                    af[mi], bf[ni], acc[mi][ni], 0, 0, 0);
    }
    #pragma unroll
    for (int mi = 0; mi < 2; mi++) {
        #pragma unroll
        for (int ni = 0; ni < 2; ni++) {
            int gcol = wn + ni * 16 + lr;
            if (gcol < 48) {
                #pragma unroll
                for (int r = 0; r < 4; r++) {
                    int grow = bm + wm + mi * 16 + quad * 4 + r;
                    dbc[(size_t)grow * 48 + gcol] = acc[mi][ni][r];
                }
            }
        }
    }
}

// -------- scan phase A: thread = (b,d,chunk); dt recomputed identically in scanC,
// so no dt export. 16 s-states in registers.
__global__ __launch_bounds__(64) void k_scanA(const bf16* __restrict__ xb,
                                              const float* __restrict__ dbc,
                                              const float* __restrict__ dtw,
                                              const float* __restrict__ dtb,
                                              const float* __restrict__ a_log,
                                              float* __restrict__ Aprod,
                                              float* __restrict__ Hfin) {
    int gid = blockIdx.x * 64 + threadIdx.x;       // 1024*NC = 131072
    int bd = gid & 1023;                           // d fast -> coalesced
    int c = gid >> 10;
    int d = bd & 511, b = bd >> 9;
    float A[16], h[16], ap[16], wdt[16];
    #pragma unroll
    for (int q = 0; q < 4; q++)
        *(float4*)&wdt[q*4] = *(const float4*)(dtw + d * 16 + q * 4);
    #pragma unroll
    for (int s = 0; s < 16; s++) {
        A[s] = -__expf(a_log[d * 16 + s]);
        h[s] = 0.f; ap[s] = 1.f;
    }
    float bdt = dtb[d];
    int tok0 = b * SEQ + c * CL;
    const bf16* xp = xb + (size_t)tok0 * 512 + d;
    const float* rp = dbc + (size_t)tok0 * 48;
    for (int t = 0; t < CL; t++) {
        float rv[32];
        #pragma unroll
        for (int q = 0; q < 8; q++) *(float4*)&rv[q*4] = *(const float4*)(rp + t * 48 + q * 4);
        float dtr = bdt;
        #pragma unroll
        for (int r = 0; r < 16; r++) dtr = fmaf(rv[r], wdt[r], dtr);
        float dtv = (dtr > 20.f) ? dtr : __logf(1.f + __expf(dtr));
        float u = dtv * bf2f(xp[t * 512]);
        #pragma unroll
        for (int s = 0; s < 16; s++) {
            float dA = __expf(dtv * A[s]);
            h[s] = fmaf(dA, h[s], u * rv[16 + s]);
            ap[s] *= dA;
        }
    }
    float* Ap = Aprod + (size_t)c * NSC + bd * 16;
    float* Hp = Hfin  + (size_t)c * NSC + bd * 16;
    #pragma unroll
    for (int q = 0; q < 4; q++) {
        *(float4*)(Ap + q * 4) = make_float4(ap[q*4], ap[q*4+1], ap[q*4+2], ap[q*4+3]);
        *(float4*)(Hp + q * 4) = make_float4(h[q*4], h[q*4+1], h[q*4+2], h[q*4+3]);
    }
}

// ---------------- scan phase B: serial combine over chunks, register-batched
// prefetch (16 chunks in flight) + 256 blocks x 64 thr (1 wave on every CU)
__global__ __launch_bounds__(64) void k_scanB(const float* __restrict__ Aprod,
                                              float* __restrict__ Hfin) {
    int chain = blockIdx.x * 64 + threadIdx.x;     // NSC
    float h = 0.f;
    for (int cg = 0; cg < NC; cg += 16) {
        float a[16], f[16];
        #pragma unroll
        for (int j = 0; j < 16; j++) {
            size_t i = (size_t)(cg + j) * NSC + chain;
            a[j] = Aprod[i];
            f[j] = Hfin[i];
        }
        #pragma unroll
        for (int j = 0; j < 16; j++) {
            size_t i = (size_t)(cg + j) * NSC + chain;
            Hfin[i] = h;
            h = fmaf(a[j], h, f[j]);
        }
    }
}

// -------- scan phase C: rescan from start state; dt recomputed bit-identically
// from dbc (same fmaf chain as scanA) -> no dtbuf round-trip.
__global__ __launch_bounds__(64) void k_scanC(const bf16* __restrict__ xb,
                                              const bf16* __restrict__ zb,
                                              const float* __restrict__ dbc,
                                              const float* __restrict__ dtw,
                                              const float* __restrict__ dtb,
                                              const float* __restrict__ a_log,
                                              const float* __restrict__ Dp,
                                              const float* __restrict__ Hstart,
                                              bf16* __restrict__ yb) {
    int gid = blockIdx.x * 64 + threadIdx.x;       // 131072
    int bd = gid & 1023;
    int c = gid >> 10;
    int d = bd & 511, b = bd >> 9;
    float A[16], h[16], wdt[16];
    const float* Hp = Hstart + (size_t)c * NSC + bd * 16;
    #pragma unroll
    for (int q = 0; q < 4; q++)
        *(float4*)&wdt[q*4] = *(const float4*)(dtw + d * 16 + q * 4);
    #pragma unroll
    for (int s = 0; s < 16; s++) {
        A[s] = -__expf(a_log[d * 16 + s]);
        h[s] = Hp[s];
    }
    float bdt = dtb[d];
    float Dv = Dp[d];
    int tok0 = b * SEQ + c * CL;
    const bf16* xp = xb + (size_t)tok0 * 512 + d;
    const bf16* zp = zb + (size_t)tok0 * 512 + d;
    const float* rp = dbc + (size_t)tok0 * 48;     // dt at +0, B at +16, C at +32
    bf16* yp = yb + (size_t)tok0 * 512 + d;
    for (int t = 0; t < CL; t++) {
        float rv[48];
        #pragma unroll
        for (int q = 0; q < 12; q++) *(float4*)&rv[q*4] = *(const float4*)(rp + t * 48 + q * 4);
        float dtr = bdt;
        #pragma unroll
        for (int r = 0; r < 16; r++) dtr = fmaf(rv[r], wdt[r], dtr);
        float dtv = (dtr > 20.f) ? dtr : __logf(1.f + __expf(dtr));
        float xv = bf2f(xp[t * 512]);
        float u = dtv * xv;
        float sum = 0.f;
        #pragma unroll
        for (int s = 0; s < 16; s++) {
            float dA = __expf(dtv * A[s]);
            h[s] = fmaf(dA, h[s], u * rv[16 + s]);
            sum = fmaf(h[s], rv[32 + s], sum);
        }
        float zv = bf2f(zp[t * 512]);
        yp[t * 512] = __float2bfloat16((sum + Dv * xv) * silu(zv));
    }
}

// ---------------------------------------------------------------- lm head
__global__ void k_head(const bf16* __restrict__ hn, const float* __restrict__ lw,
                       float* __restrict__ out) {
    int idx = blockIdx.x * 256 + threadIdx.x;      // NTOK*20 = 81920
    int tok = idx / 20, v = idx % 20;
    const short* a = (const short*)(hn + (size_t)tok * 256);
    const float* w = lw + (size_t)v * 256;
    float acc = 0.f;
    for (int k = 0; k < 256; k += 8) {
        short8 a8 = *(const short8*)(a + k);
        #pragma unroll
        for (int j = 0; j < 8; j++) acc = fmaf(bfs2f(a8[j]), w[k + j], acc);
    }
    out[idx] = acc;
}

extern "C" void kernel_launch(void* const* d_in, const int* in_sizes, int n_in,
                              void* d_out, int out_size, void* d_ws, size_t ws_size,
                              hipStream_t stream) {
    const int*   ids    = (const int*)d_in[0];
    const float* emb    = (const float*)d_in[1];
    const float* in_w   = (const float*)d_in[2];
    const float* conv_w = (const float*)d_in[3];
    const float* conv_b = (const float*)d_in[4];
    const float* x_w    = (const float*)d_in[5];
    const float* dt_w   = (const float*)d_in[6];
    const float* dt_b   = (const float*)d_in[7];
    const float* a_log  = (const float*)d_in[8];
    const float* d_skip = (const float*)d_in[9];
    const float* out_w  = (const float*)d_in[10];
    const float* norm_w = (const float*)d_in[11];
    const float* norm_f = (const float*)d_in[12];
    const float* lm_w   = (const float*)d_in[13];
    float* out = (float*)d_out;

    // ---- workspace layout ----
    char* ws = (char*)d_ws;
    float* residual = (float*)(ws + 0);            // 4 MB
    bf16*  hn       = (bf16*) (ws + 4194304);      // 2 MB
    bf16*  xh       = (bf16*) (ws + 6291456);      // 4 MB (alias: yb)
    bf16*  zb       = (bf16*) (ws + 10485760);     // 4 MB
    bf16*  xb       = (bf16*) (ws + 14680064);     // 4 MB
    float* dbc      = (float*)(ws + 18874368);     // 768 KB
    float* Aprod    = (float*)(ws + 23855104);     // 8 MB
    float* Hfin     = (float*)(ws + 32243712);     // 8 MB
    short* in_wb    = (short*)(ws + 40632320);     // 8 MB  (16 layers bf16)
    short* out_wb   = (short*)(ws + 49020928);     // 4 MB
    short* x_wb     = (short*)(ws + 53215232);     // 768 KB -> end 54,001,664
    bf16*  yb       = xh;

    k_wcvt_all<<<6684672 / 256, 256, 0, stream>>>(in_w, out_w, x_w, in_wb, out_wb, x_wb);
    k_embed<<<(NTOK * 256) / 256, 256, 0, stream>>>(ids, emb, residual);

    for (int i = 0; i < N_LAYER; i++) {
        k_rmsnorm<<<NTOK, 256, 0, stream>>>(residual, norm_w + i * D_MODEL, hn);
        dim3 g1(NTOK / 64, 1024 / 64);
        k_gemm1_mfma<<<g1, 256, 0, stream>>>(hn, in_wb + (size_t)i * 262144, xh, zb);
        k_conv<<<(512 * NTOK / 4) / 256, 256, 0, stream>>>(
            xh, conv_w + (size_t)i * 512 * 4, conv_b + (size_t)i * 512, xb);
        k_xproj_mfma<<<NTOK / 64, 256, 0, stream>>>(xb, x_wb + (size_t)i * 24576, dbc);
        k_scanA<<<(1024 * NC) / 64, 64, 0, stream>>>(
            xb, dbc, dt_w + (size_t)i * 512 * 16, dt_b + (size_t)i * 512,
            a_log + (size_t)i * 512 * 16, Aprod, Hfin);
        k_scanB<<<NSC / 64, 64, 0, stream>>>(Aprod, Hfin);
        k_scanC<<<(1024 * NC) / 64, 64, 0, stream>>>(
            xb, zb, dbc, dt_w + (size_t)i * 512 * 16, dt_b + (size_t)i * 512,
            a_log + (size_t)i * 512 * 16, d_skip + (size_t)i * 512, Hfin, yb);
        dim3 g2(NTOK / 64, 256 / 64);
        k_gemm2_mfma<<<g2, 256, 0, stream>>>(yb, out_wb + (size_t)i * 131072, residual);
    }

    k_rmsnorm<<<NTOK, 256, 0, stream>>>(residual, norm_f, hn);
    k_head<<<320, 256, 0, stream>>>(hn, lm_w, out);
}

// Round 3
// 1419.121 us; speedup vs baseline: 1.2711x; 1.0272x over previous
//
#include <hip/hip_runtime.h>
#include <hip/hip_bf16.h>

#define D_MODEL 256
#define N_LAYER 16
#define VOCAB 24
#define D_INNER 512
#define D_STATE 16
#define D_CONV 4
#define DT_RANK 16
#define BATCH 2
#define SEQ 2048
#define NTOK (BATCH*SEQ)   /* 4096 */
#define EPS 1e-5f
#define NC 128             /* scan chunks per sequence */
#define CL (SEQ/NC)        /* 16 tokens per chunk */
#define NSC (BATCH*D_INNER*D_STATE)      /* 16384 scan chains */

typedef __hip_bfloat16 bf16;
typedef __attribute__((ext_vector_type(8))) short short8;
typedef __attribute__((ext_vector_type(4))) float f32x4;

__device__ __forceinline__ float silu(float v) { return v / (1.f + __expf(-v)); }
__device__ __forceinline__ float bf2f(bf16 v) { return __bfloat162float(v); }
__device__ __forceinline__ float bfs2f(short s) {         // raw bf16 bits -> f32
    return __uint_as_float(((unsigned)(unsigned short)s) << 16);
}
__device__ __forceinline__ short bfr(float x) {           // f32 -> bf16 RNE
    unsigned u = __float_as_uint(x);
    return (short)((u + 0x7fffu + ((u >> 16) & 1u)) >> 16);
}

// ------------- ALL-layer weight pre-convert: f32 -> bf16, one pass
__global__ void k_wcvt_all(const float* __restrict__ in_w, const float* __restrict__ out_w,
                           const float* __restrict__ x_w, short* __restrict__ in_wb,
                           short* __restrict__ out_wb, short* __restrict__ x_wb) {
    int idx = blockIdx.x * 256 + threadIdx.x;      // 6,684,672 total
    if (idx < 4194304) {
        in_wb[idx] = bfr(in_w[idx]);
    } else if (idx < 4194304 + 2097152) {
        int j = idx - 4194304;
        out_wb[j] = bfr(out_w[j]);
    } else {
        int j = idx - 4194304 - 2097152;           // < 393216
        x_wb[j] = bfr(x_w[j]);
    }
}

// -------------------------------- embedding; also seeds nsum (row sumsq) for layer 0
__global__ void k_embed(const int* __restrict__ ids, const float* __restrict__ emb,
                        float* __restrict__ residual, float* __restrict__ nsum) {
    __shared__ float wred[4];
    int tok = blockIdx.x, c = threadIdx.x;         // grid = NTOK, 256 thr
    float v = emb[ids[tok] * D_MODEL + c];
    residual[tok * 256 + c] = v;
    float s = v * v;
    #pragma unroll
    for (int off = 32; off >= 1; off >>= 1) s += __shfl_xor(s, off);
    if ((c & 63) == 0) wred[c >> 6] = s;
    __syncthreads();
    if (c == 0) {
        float tot = wred[0] + wred[1] + wred[2] + wred[3];
        *(float4*)(nsum + (size_t)tok * 4) = make_float4(tot, 0.f, 0.f, 0.f);
    }
}

// ------------------------------------------- final rmsnorm -> bf16 hn (standalone)
__global__ void k_rmsnorm(const float* __restrict__ residual, const float* __restrict__ w,
                          bf16* __restrict__ hn) {
    __shared__ float wred[4];
    int tok = blockIdx.x, c = threadIdx.x;
    float v = residual[tok * 256 + c];
    float s = v * v;
    #pragma unroll
    for (int off = 32; off >= 1; off >>= 1) s += __shfl_xor(s, off);
    if ((c & 63) == 0) wred[c >> 6] = s;
    __syncthreads();
    float tot = wred[0] + wred[1] + wred[2] + wred[3];
    float scale = rsqrtf(tot * (1.f / 256.f) + EPS);
    hn[tok * 256 + c] = __float2bfloat16(v * scale * w[c]);
}

// ---- gemm1 MFMA with FUSED rmsnorm: A = rmsnorm(residual)*norm_w -> bf16 staging
// [NTOK,256] @ [1024,256]^T -> xh/zb bf16
__global__ __launch_bounds__(256) void k_gemm1_mfma(const float* __restrict__ Rres,
                                                    const float* __restrict__ nsum,
                                                    const float* __restrict__ nw,
                                                    const short* __restrict__ W16,
                                                    bf16* __restrict__ xh,
                                                    bf16* __restrict__ zb) {
    __shared__ short AsL[64 * 40];   // [row][40] bf16, pad 32->40
    __shared__ short WsL[64 * 40];
    const int bm = blockIdx.x * 64, bn = blockIdx.y * 64;
    const int tid = threadIdx.x;
    const int wave = tid >> 6, lane = tid & 63;
    const int wm = (wave & 1) * 32, wn = (wave >> 1) * 32;
    const int quad = lane >> 4, lr = lane & 15;
    const int srow = tid >> 2, skq = (tid & 3) * 8;
    const float4 ns = *(const float4*)(nsum + (size_t)(bm + srow) * 4);
    const float scale = rsqrtf((ns.x + ns.y + ns.z + ns.w) * (1.f / 256.f) + EPS);
    f32x4 acc[2][2] = {};
    for (int k0 = 0; k0 < 256; k0 += 32) {
        float av[8], wv[8];
        *(float4*)&av[0] = *(const float4*)(Rres + (size_t)(bm + srow) * 256 + k0 + skq);
        *(float4*)&av[4] = *(const float4*)(Rres + (size_t)(bm + srow) * 256 + k0 + skq + 4);
        *(float4*)&wv[0] = *(const float4*)(nw + k0 + skq);
        *(float4*)&wv[4] = *(const float4*)(nw + k0 + skq + 4);
        short8 a8;
        #pragma unroll
        for (int j = 0; j < 8; j++) a8[j] = bfr(av[j] * scale * wv[j]);
        short8 w8 = *(const short8*)(W16 + (size_t)(bn + srow) * 256 + k0 + skq);
        __syncthreads();
        *(short8*)&AsL[srow * 40 + skq] = a8;
        *(short8*)&WsL[srow * 40 + skq] = w8;
        __syncthreads();
        short8 af[2], bf[2];
        #pragma unroll
        for (int i = 0; i < 2; i++) {
            af[i] = *(const short8*)&AsL[(wm + i * 16 + lr) * 40 + quad * 8];
            bf[i] = *(const short8*)&WsL[(wn + i * 16 + lr) * 40 + quad * 8];
        }
        #pragma unroll
        for (int mi = 0; mi < 2; mi++)
            #pragma unroll
            for (int ni = 0; ni < 2; ni++)
                acc[mi][ni] = __builtin_amdgcn_mfma_f32_16x16x32_bf16(
                    af[mi], bf[ni], acc[mi][ni], 0, 0, 0);
    }
    #pragma unroll
    for (int mi = 0; mi < 2; mi++) {
        #pragma unroll
        for (int ni = 0; ni < 2; ni++) {
            int gcol = bn + wn + ni * 16 + lr;
            #pragma unroll
            for (int r = 0; r < 4; r++) {
                int grow = bm + wm + mi * 16 + quad * 4 + r;
                float v = acc[mi][ni][r];
                if (bn < 512) xh[(size_t)grow * 512 + gcol] = __float2bfloat16(v);
                else          zb[(size_t)grow * 512 + gcol - 512] = __float2bfloat16(v);
            }
        }
    }
}

// ---- gemm2 MFMA: residual += [NTOK,512]bf16 @ [256,512]^T bf16
// FUSED epilogue: per-row partial sumsq of the UPDATED residual -> nsum[tok][bny]
__global__ __launch_bounds__(256) void k_gemm2_mfma(const bf16* __restrict__ Abf,
                                                    const short* __restrict__ W16,
                                                    float* __restrict__ residual,
                                                    float* __restrict__ nsum) {
    __shared__ short AsL[64 * 40];
    __shared__ short WsL[64 * 40];
    __shared__ float rsum[64][2];
    const short* A16 = (const short*)Abf;
    const int bm = blockIdx.x * 64, bn = blockIdx.y * 64;
    const int tid = threadIdx.x;
    const int wave = tid >> 6, lane = tid & 63;
    const int wm = (wave & 1) * 32, wn = (wave >> 1) * 32;
    const int quad = lane >> 4, lr = lane & 15;
    const int srow = tid >> 2, skq = (tid & 3) * 8;
    f32x4 acc[2][2] = {};
    for (int k0 = 0; k0 < 512; k0 += 32) {
        short8 a8 = *(const short8*)(A16 + (size_t)(bm + srow) * 512 + k0 + skq);
        short8 w8 = *(const short8*)(W16 + (size_t)(bn + srow) * 512 + k0 + skq);
        __syncthreads();
        *(short8*)&AsL[srow * 40 + skq] = a8;
        *(short8*)&WsL[srow * 40 + skq] = w8;
        __syncthreads();
        short8 af[2], bf[2];
        #pragma unroll
        for (int i = 0; i < 2; i++) {
            af[i] = *(const short8*)&AsL[(wm + i * 16 + lr) * 40 + quad * 8];
            bf[i] = *(const short8*)&WsL[(wn + i * 16 + lr) * 40 + quad * 8];
        }
        #pragma unroll
        for (int mi = 0; mi < 2; mi++)
            #pragma unroll
            for (int ni = 0; ni < 2; ni++)
                acc[mi][ni] = __builtin_amdgcn_mfma_f32_16x16x32_bf16(
                    af[mi], bf[ni], acc[mi][ni], 0, 0, 0);
    }
    float sq[2][4] = {};
    #pragma unroll
    for (int mi = 0; mi < 2; mi++) {
        #pragma unroll
        for (int ni = 0; ni < 2; ni++) {
            int gcol = bn + wn + ni * 16 + lr;
            #pragma unroll
            for (int r = 0; r < 4; r++) {
                int grow = bm + wm + mi * 16 + quad * 4 + r;
                size_t idx = (size_t)grow * 256 + gcol;
                float v = residual[idx] + acc[mi][ni][r];
                residual[idx] = v;
                sq[mi][r] += v * v;
            }
        }
    }
    #pragma unroll
    for (int off = 1; off < 16; off <<= 1) {
        #pragma unroll
        for (int mi = 0; mi < 2; mi++)
            #pragma unroll
            for (int r = 0; r < 4; r++)
                sq[mi][r] += __shfl_xor(sq[mi][r], off);
    }
    if (lr == 0) {
        #pragma unroll
        for (int mi = 0; mi < 2; mi++)
            #pragma unroll
            for (int r = 0; r < 4; r++)
                rsum[wm + mi * 16 + quad * 4 + r][wave >> 1] = sq[mi][r];
    }
    __syncthreads();
    if (tid < 64)
        nsum[(size_t)(bm + tid) * 4 + blockIdx.y] = rsum[tid][0] + rsum[tid][1];
}

// ---------------- depthwise conv + silu: thread = (d, 4 consecutive tokens)
__global__ void k_conv(const bf16* __restrict__ xh, const float* __restrict__ cw,
                       const float* __restrict__ cb, bf16* __restrict__ xb) {
    int gid = blockIdx.x * 256 + threadIdx.x;      // 512 * NTOK/4 = 524288
    int d = gid & 511;
    int tq = gid >> 9;                             // 0..1023
    int tok0 = tq * 4;                             // 4 | 2048: no batch crossing
    int b = tok0 >> 11, l0 = tok0 & 2047;
    float4 cwv = *(const float4*)(cw + d * 4);
    float cbv = cb[d];
    const bf16* base = xh + ((size_t)(b << 11)) * 512 + d;
    float xv[7];
    #pragma unroll
    for (int i = 0; i < 7; i++) {
        int lt = l0 - 3 + i;
        xv[i] = (lt >= 0) ? bf2f(base[(size_t)lt * 512]) : 0.f;
    }
    bf16* dst = xb + (size_t)tok0 * 512 + d;
    #pragma unroll
    for (int t = 0; t < 4; t++) {
        float acc = cbv + xv[t] * cwv.x + xv[t+1] * cwv.y + xv[t+2] * cwv.z + xv[t+3] * cwv.w;
        dst[(size_t)t * 512] = __float2bfloat16(silu(acc));
    }
}

// ---------------- x_proj MFMA, M-tile 32 (128 blocks): dbc[NTOK,48] = xb @ xw^T
__global__ __launch_bounds__(256) void k_xproj_mfma(const bf16* __restrict__ Abf,
                                                    const short* __restrict__ W16,
                                                    float* __restrict__ dbc) {
    __shared__ short AsL[32 * 40];
    __shared__ short WsL[64 * 40];
    const short* A16 = (const short*)Abf;
    const int bm = blockIdx.x * 32;
    const int tid = threadIdx.x;
    const int wave = tid >> 6, lane = tid & 63;
    const int wm = (wave & 1) * 16, wn = (wave >> 1) * 32;
    const int quad = lane >> 4, lr = lane & 15;
    const int srow = tid >> 2, skq = (tid & 3) * 8;   // srow 0..63
    f32x4 acc[2] = {};
    for (int k0 = 0; k0 < 512; k0 += 32) {
        short8 a8, w8;
        if (srow < 32) a8 = *(const short8*)(A16 + (size_t)(bm + srow) * 512 + k0 + skq);
        if (srow < 48) w8 = *(const short8*)(W16 + (size_t)srow * 512 + k0 + skq);
        __syncthreads();
        if (srow < 32) *(short8*)&AsL[srow * 40 + skq] = a8;
        if (srow < 48) *(short8*)&WsL[srow * 40 + skq] = w8;
        __syncthreads();
        short8 af = *(const short8*)&AsL[(wm + lr) * 40 + quad * 8];
        #pragma unroll
        for (int ni = 0; ni < 2; ni++) {
            short8 bfv = *(const short8*)&WsL[(wn + ni * 16 + lr) * 40 + quad * 8];
            acc[ni] = __builtin_amdgcn_mfma_f32_16x16x32_bf16(af, bfv, acc[ni], 0, 0, 0);
        }
    }
    #pragma unroll
    for (int ni = 0; ni < 2; ni++) {
        int gcol = wn + ni * 16 + lr;
        if (gcol < 48) {
            #pragma unroll
            for (int r = 0; r < 4; r++) {
                int grow = bm + wm + quad * 4 + r;
                dbc[(size_t)grow * 48 + gcol] = acc[ni][r];
            }
        }
    }
}

// -------- scan phase A: thread = (b,d,chunk); dt recomputed identically in scanC,
// so no dt export. 16 s-states in registers.
__global__ __launch_bounds__(64) void k_scanA(const bf16* __restrict__ xb,
                                              const float* __restrict__ dbc,
                                              const float* __restrict__ dtw,
                                              const float* __restrict__ dtb,
                                              const float* __restrict__ a_log,
                                              float* __restrict__ Aprod,
                                              float* __restrict__ Hfin) {
    int gid = blockIdx.x * 64 + threadIdx.x;       // 1024*NC = 131072
    int bd = gid & 1023;                           // d fast -> coalesced
    int c = gid >> 10;
    int d = bd & 511, b = bd >> 9;
    float A[16], h[16], ap[16], wdt[16];
    #pragma unroll
    for (int q = 0; q < 4; q++)
        *(float4*)&wdt[q*4] = *(const float4*)(dtw + d * 16 + q * 4);
    #pragma unroll
    for (int s = 0; s < 16; s++) {
        A[s] = -__expf(a_log[d * 16 + s]);
        h[s] = 0.f; ap[s] = 1.f;
    }
    float bdt = dtb[d];
    int tok0 = b * SEQ + c * CL;
    const bf16* xp = xb + (size_t)tok0 * 512 + d;
    const float* rp = dbc + (size_t)tok0 * 48;
    for (int t = 0; t < CL; t++) {
        float rv[32];
        #pragma unroll
        for (int q = 0; q < 8; q++) *(float4*)&rv[q*4] = *(const float4*)(rp + t * 48 + q * 4);
        float dtr = bdt;
        #pragma unroll
        for (int r = 0; r < 16; r++) dtr = fmaf(rv[r], wdt[r], dtr);
        float dtv = (dtr > 20.f) ? dtr : __logf(1.f + __expf(dtr));
        float u = dtv * bf2f(xp[t * 512]);
        #pragma unroll
        for (int s = 0; s < 16; s++) {
            float dA = __expf(dtv * A[s]);
            h[s] = fmaf(dA, h[s], u * rv[16 + s]);
            ap[s] *= dA;
        }
    }
    float* Ap = Aprod + (size_t)c * NSC + bd * 16;
    float* Hp = Hfin  + (size_t)c * NSC + bd * 16;
    #pragma unroll
    for (int q = 0; q < 4; q++) {
        *(float4*)(Ap + q * 4) = make_float4(ap[q*4], ap[q*4+1], ap[q*4+2], ap[q*4+3]);
        *(float4*)(Hp + q * 4) = make_float4(h[q*4], h[q*4+1], h[q*4+2], h[q*4+3]);
    }
}

// ---------------- scan phase B: serial combine over chunks, register-batched
__global__ __launch_bounds__(64) void k_scanB(const float* __restrict__ Aprod,
                                              float* __restrict__ Hfin) {
    int chain = blockIdx.x * 64 + threadIdx.x;     // NSC
    float h = 0.f;
    for (int cg = 0; cg < NC; cg += 16) {
        float a[16], f[16];
        #pragma unroll
        for (int j = 0; j < 16; j++) {
            size_t i = (size_t)(cg + j) * NSC + chain;
            a[j] = Aprod[i];
            f[j] = Hfin[i];
        }
        #pragma unroll
        for (int j = 0; j < 16; j++) {
            size_t i = (size_t)(cg + j) * NSC + chain;
            Hfin[i] = h;
            h = fmaf(a[j], h, f[j]);
        }
    }
}

// -------- scan phase C: rescan from start state; dt recomputed bit-identically
__global__ __launch_bounds__(64) void k_scanC(const bf16* __restrict__ xb,
                                              const bf16* __restrict__ zb,
                                              const float* __restrict__ dbc,
                                              const float* __restrict__ dtw,
                                              const float* __restrict__ dtb,
                                              const float* __restrict__ a_log,
                                              const float* __restrict__ Dp,
                                              const float* __restrict__ Hstart,
                                              bf16* __restrict__ yb) {
    int gid = blockIdx.x * 64 + threadIdx.x;       // 131072
    int bd = gid & 1023;
    int c = gid >> 10;
    int d = bd & 511, b = bd >> 9;
    float A[16], h[16], wdt[16];
    const float* Hp = Hstart + (size_t)c * NSC + bd * 16;
    #pragma unroll
    for (int q = 0; q < 4; q++)
        *(float4*)&wdt[q*4] = *(const float4*)(dtw + d * 16 + q * 4);
    #pragma unroll
    for (int s = 0; s < 16; s++) {
        A[s] = -__expf(a_log[d * 16 + s]);
        h[s] = Hp[s];
    }
    float bdt = dtb[d];
    float Dv = Dp[d];
    int tok0 = b * SEQ + c * CL;
    const bf16* xp = xb + (size_t)tok0 * 512 + d;
    const bf16* zp = zb + (size_t)tok0 * 512 + d;
    const float* rp = dbc + (size_t)tok0 * 48;     // dt at +0, B at +16, C at +32
    bf16* yp = yb + (size_t)tok0 * 512 + d;
    for (int t = 0; t < CL; t++) {
        float rv[48];
        #pragma unroll
        for (int q = 0; q < 12; q++) *(float4*)&rv[q*4] = *(const float4*)(rp + t * 48 + q * 4);
        float dtr = bdt;
        #pragma unroll
        for (int r = 0; r < 16; r++) dtr = fmaf(rv[r], wdt[r], dtr);
        float dtv = (dtr > 20.f) ? dtr : __logf(1.f + __expf(dtr));
        float xv = bf2f(xp[t * 512]);
        float u = dtv * xv;
        float sum = 0.f;
        #pragma unroll
        for (int s = 0; s < 16; s++) {
            float dA = __expf(dtv * A[s]);
            h[s] = fmaf(dA, h[s], u * rv[16 + s]);
            sum = fmaf(h[s], rv[32 + s], sum);
        }
        float zv = bf2f(zp[t * 512]);
        yp[t * 512] = __float2bfloat16((sum + Dv * xv) * silu(zv));
    }
}

// ---------------------------------------------------------------- lm head
__global__ void k_head(const bf16* __restrict__ hn, const float* __restrict__ lw,
                       float* __restrict__ out) {
    int idx = blockIdx.x * 256 + threadIdx.x;      // NTOK*20 = 81920
    int tok = idx / 20, v = idx % 20;
    const short* a = (const short*)(hn + (size_t)tok * 256);
    const float* w = lw + (size_t)v * 256;
    float acc = 0.f;
    for (int k = 0; k < 256; k += 8) {
        short8 a8 = *(const short8*)(a + k);
        #pragma unroll
        for (int j = 0; j < 8; j++) acc = fmaf(bfs2f(a8[j]), w[k + j], acc);
    }
    out[idx] = acc;
}

extern "C" void kernel_launch(void* const* d_in, const int* in_sizes, int n_in,
                              void* d_out, int out_size, void* d_ws, size_t ws_size,
                              hipStream_t stream) {
    const int*   ids    = (const int*)d_in[0];
    const float* emb    = (const float*)d_in[1];
    const float* in_w   = (const float*)d_in[2];
    const float* conv_w = (const float*)d_in[3];
    const float* conv_b = (const float*)d_in[4];
    const float* x_w    = (const float*)d_in[5];
    const float* dt_w   = (const float*)d_in[6];
    const float* dt_b   = (const float*)d_in[7];
    const float* a_log  = (const float*)d_in[8];
    const float* d_skip = (const float*)d_in[9];
    const float* out_w  = (const float*)d_in[10];
    const float* norm_w = (const float*)d_in[11];
    const float* norm_f = (const float*)d_in[12];
    const float* lm_w   = (const float*)d_in[13];
    float* out = (float*)d_out;

    // ---- workspace layout ----
    char* ws = (char*)d_ws;
    float* residual = (float*)(ws + 0);            // 4 MB
    bf16*  hn       = (bf16*) (ws + 4194304);      // 2 MB
    bf16*  xh       = (bf16*) (ws + 6291456);      // 4 MB (alias: yb)
    bf16*  zb       = (bf16*) (ws + 10485760);     // 4 MB
    bf16*  xb       = (bf16*) (ws + 14680064);     // 4 MB
    float* dbc      = (float*)(ws + 18874368);     // 768 KB
    float* Aprod    = (float*)(ws + 23855104);     // 8 MB
    float* Hfin     = (float*)(ws + 32243712);     // 8 MB
    short* in_wb    = (short*)(ws + 40632320);     // 8 MB  (16 layers bf16)
    short* out_wb   = (short*)(ws + 49020928);     // 4 MB
    short* x_wb     = (short*)(ws + 53215232);     // 768 KB
    float* nsum     = (float*)(ws + 54001664);     // 64 KB [tok][4] -> end 54,067,200
    bf16*  yb       = xh;

    k_wcvt_all<<<6684672 / 256, 256, 0, stream>>>(in_w, out_w, x_w, in_wb, out_wb, x_wb);
    k_embed<<<NTOK, 256, 0, stream>>>(ids, emb, residual, nsum);

    for (int i = 0; i < N_LAYER; i++) {
        dim3 g1(NTOK / 64, 1024 / 64);
        k_gemm1_mfma<<<g1, 256, 0, stream>>>(residual, nsum, norm_w + i * D_MODEL,
                                             in_wb + (size_t)i * 262144, xh, zb);
        k_conv<<<(512 * NTOK / 4) / 256, 256, 0, stream>>>(
            xh, conv_w + (size_t)i * 512 * 4, conv_b + (size_t)i * 512, xb);
        k_xproj_mfma<<<NTOK / 32, 256, 0, stream>>>(xb, x_wb + (size_t)i * 24576, dbc);
        k_scanA<<<(1024 * NC) / 64, 64, 0, stream>>>(
            xb, dbc, dt_w + (size_t)i * 512 * 16, dt_b + (size_t)i * 512,
            a_log + (size_t)i * 512 * 16, Aprod, Hfin);
        k_scanB<<<NSC / 64, 64, 0, stream>>>(Aprod, Hfin);
        k_scanC<<<(1024 * NC) / 64, 64, 0, stream>>>(
            xb, zb, dbc, dt_w + (size_t)i * 512 * 16, dt_b + (size_t)i * 512,
            a_log + (size_t)i * 512 * 16, d_skip + (size_t)i * 512, Hfin, yb);
        dim3 g2(NTOK / 64, 256 / 64);
        k_gemm2_mfma<<<g2, 256, 0, stream>>>(yb, out_wb + (size_t)i * 131072,
                                             residual, nsum);
    }

    k_rmsnorm<<<NTOK, 256, 0, stream>>>(residual, norm_f, hn);
    k_head<<<320, 256, 0, stream>>>(hn, lm_w, out);
}